// Round 9
// baseline (66.731 us; speedup 1.0000x reference)
//
#include <hip/hip_runtime.h>
#include <hip/hip_bf16.h>

#define NN 4096
#define SJ 8
#define JCH (NN / SJ)        // 512
#define JSTEP 64
#define NSTEPS (JCH / JSTEP) // 8
#define ROWS 16
#define LOG2E 1.44269504f

typedef __attribute__((ext_vector_type(4))) float f32x4;
typedef __attribute__((ext_vector_type(4))) int i32x4;
typedef __attribute__((ext_vector_type(4))) unsigned int u32x4;
typedef __attribute__((ext_vector_type(8))) short short8;

// packed bf16 pair: (lo=bf16(a), hi=bf16(b)) in one dword (v_cvt_pk_bf16_f32)
__device__ __forceinline__ unsigned pk2(float a, float b) {
    float2 t; t.x = a; t.y = b;
    __hip_bfloat162 h = __float22bfloat162_rn(t);
    unsigned r;
    __builtin_memcpy(&r, &h, 4);
    return r;
}

__device__ __forceinline__ short8 load8_bf(const float* __restrict__ p) {
    f32x4 a = *(const f32x4*)p;
    f32x4 b = *(const f32x4*)(p + 4);
    u32x4 v = {pk2(a[0], a[1]), pk2(a[2], a[3]), pk2(b[0], b[1]), pk2(b[2], b[3])};
    return __builtin_bit_cast(short8, v);
}

// Kernel 1: h = x @ W^T (bf16 MFMA). Epilogue:
//   Rt[h][i]  = exp(-0.8*es_i)   (f32; exp(es) factor cancels in softmax)
//   BDt[h][j] = pack_bf16(exp(ed_j), exp(0.2*ed_j))
//   hT[h*32+d][j] = bf16 h, transposed via per-wave LDS tile (coalesced stores)
__global__ __launch_bounds__(256) void k1_proj(
        const float* __restrict__ x, const float* __restrict__ W,
        const float* __restrict__ asrc, const float* __restrict__ adst,
        unsigned short* __restrict__ hT, float* __restrict__ Rt,
        unsigned* __restrict__ BDt) {
    __shared__ unsigned short ttile[4][32][16];   // 4 KB
    const int ibase = blockIdx.x * 16;
    const int w = threadIdx.x >> 6;
    const int lane = threadIdx.x & 63;
    const int grp = lane >> 4, li = lane & 15;

    const float* xrow = x + (ibase + li) * 128;
    const float* w0 = W + (w * 32 + li) * 128;
    const float* w1 = W + (w * 32 + 16 + li) * 128;

    f32x4 c0 = {0.f, 0.f, 0.f, 0.f}, c1 = {0.f, 0.f, 0.f, 0.f};
#pragma unroll
    for (int ko = 0; ko < 128; ko += 32) {
        const int kk = ko + grp * 8;
        short8 a = load8_bf(xrow + kk);
        short8 b0 = load8_bf(w0 + kk);
        short8 b1 = load8_bf(w1 + kk);
        c0 = __builtin_amdgcn_mfma_f32_16x16x32_bf16(a, b0, c0, 0, 0, 0);
        c1 = __builtin_amdgcn_mfma_f32_16x16x32_bf16(a, b1, c1, 0, 0, 0);
    }
    const float as0 = asrc[w * 32 + li], as1 = asrc[w * 32 + 16 + li];
    const float ad0 = adst[w * 32 + li], ad1 = adst[w * 32 + 16 + li];
    float pes[4], ped[4];
#pragma unroll
    for (int r = 0; r < 4; ++r) {
        pes[r] = c0[r] * as0 + c1[r] * as1;
        ped[r] = c0[r] * ad0 + c1[r] * ad1;
    }
#pragma unroll
    for (int m = 1; m < 16; m <<= 1) {
#pragma unroll
        for (int r = 0; r < 4; ++r) {
            pes[r] += __shfl_xor(pes[r], m);
            ped[r] += __shfl_xor(ped[r], m);
        }
    }
    if (li == 0) {
#pragma unroll
        for (int r = 0; r < 4; ++r) {
            const int row = ibase + grp * 4 + r;
            Rt[w * NN + row] = __builtin_amdgcn_exp2f(-0.8f * LOG2E * pes[r]);
            const float Bv = __builtin_amdgcn_exp2f(LOG2E * ped[r]);
            const float Dv = __builtin_amdgcn_exp2f(0.2f * LOG2E * ped[r]);
            BDt[w * NN + row] = pk2(Bv, Dv);
        }
    }
    unsigned short* tw = &ttile[w][0][0];
    {
        uint2 v0; v0.x = pk2(c0[0], c0[1]); v0.y = pk2(c0[2], c0[3]);
        uint2 v1; v1.x = pk2(c1[0], c1[1]); v1.y = pk2(c1[2], c1[3]);
        *(uint2*)&tw[li * 16 + grp * 4] = v0;
        *(uint2*)&tw[(li + 16) * 16 + grp * 4] = v1;
    }
    __syncthreads();
    const int d = lane >> 1, half = lane & 1;
    u32x4 v = *(const u32x4*)&ttile[w][d][half * 8];
    *(u32x4*)(hT + (size_t)(w * 32 + d) * NN + ibase + half * 8) = v;
}

// per-step register payload (loaded 1 step ahead, 2 slots, static indexing)
struct SR {
    short8 t00, t01, t10, t11;   // hT rows d=li (ks=0,1), d=li+16 (ks=0,1)
    u32x4 b0a, b0b, b1a, b1b;    // packed BD slices: ks=0 (8 j), ks=1
};

// q = adj * max(B, R*D) from packed bf16 {B,D}: shl/and unpack + mul/max/mask.
__device__ __forceinline__ short8 buildQ(float R, const u32x4 ba, const u32x4 bb,
                                         const i32x4 q0, const i32x4 q1) {
    float p[8];
#pragma unroll
    for (int e = 0; e < 4; ++e) {
        const unsigned v = ba[e];
        const float B = __builtin_bit_cast(float, v << 16);
        const float D = __builtin_bit_cast(float, v & 0xFFFF0000u);
        const float m = fmaxf(B, R * D);
        p[e] = __builtin_bit_cast(float, __builtin_bit_cast(unsigned, m) & (0u - (unsigned)q0[e]));
    }
#pragma unroll
    for (int e = 0; e < 4; ++e) {
        const unsigned v = bb[e];
        const float B = __builtin_bit_cast(float, v << 16);
        const float D = __builtin_bit_cast(float, v & 0xFFFF0000u);
        const float m = fmaxf(B, R * D);
        p[4 + e] = __builtin_bit_cast(float, __builtin_bit_cast(unsigned, m) & (0u - (unsigned)q1[e]));
    }
    u32x4 u = {pk2(p[0], p[1]), pk2(p[2], p[3]), pk2(p[4], p[5]), pk2(p[6], p[7])};
    return __builtin_bit_cast(short8, u);
}

// Kernel 3: grid (256 i-tiles of 16 rows, SJ) x 256 thr, wave = head.
// Occupancy-first: 12 KB LDS + VGPR<=128 (launch_bounds(256,4)) -> 4 blocks/CU
// resident, 16 waves/CU. adj [16][64] triple-buffered via global_load_lds
// (1 issue/wave/step: lane -> row head*4+grp, chunk li, source-swizzled
// c = li ^ row so LDS stays linear per rule 21). Tables prefetched to regs
// 1 step ahead (2 static slots). Counted vmcnt(1) keeps stage(t+2) in flight.
__global__ __launch_bounds__(256, 4) void k3_main(
        const int* __restrict__ adj, const unsigned short* __restrict__ hT,
        const float* __restrict__ Rt, const unsigned* __restrict__ BDt,
        float* __restrict__ numer, float* __restrict__ denom) {
    __shared__ unsigned int adjbuf[3][ROWS * 64];   // 3 x 4 KB

    const int ibase = blockIdx.x * ROWS;
    const int jstart = blockIdx.y * JCH;
    const int head = threadIdx.x >> 6;
    const int lane = threadIdx.x & 63;
    const int grp = lane >> 4, li = lane & 15;

    const float Rv = Rt[head * NN + ibase + li];
    const unsigned short* h0 = hT + (size_t)(head * 32 + li) * NN + jstart;
    const unsigned short* h1 = hT + (size_t)(head * 32 + 16 + li) * NN + jstart;
    const unsigned* bd = BDt + head * NN + jstart;
    const unsigned int* adju = (const unsigned int*)adj;

    // staging source: this lane stages tile-row head*4+grp, position li,
    // holding global chunk c = li ^ (row&15)
    const int srow = head * 4 + grp;
    const unsigned int* gsrc = adju + (size_t)(ibase + srow) * NN + jstart + (li ^ srow) * 4;

    f32x4 c0 = {0.f,0.f,0.f,0.f}, c1 = {0.f,0.f,0.f,0.f}, dn = {0.f,0.f,0.f,0.f};
    short8 bones;
#pragma unroll
    for (int e = 0; e < 8; ++e) bones[e] = (short)0x3F80;  // bf16 1.0

    auto stage = [&](int slot, int toff) {
        __builtin_amdgcn_global_load_lds(gsrc + toff, &adjbuf[slot][head * 4 * 64], 16, 0, 0);
    };
    auto loadR = [&](int toff) {
        SR r;
        r.t00 = *(const short8*)(h0 + toff + grp * 8);
        r.t01 = *(const short8*)(h0 + toff + 32 + grp * 8);
        r.t10 = *(const short8*)(h1 + toff + grp * 8);
        r.t11 = *(const short8*)(h1 + toff + 32 + grp * 8);
        r.b0a = *(const u32x4*)(bd + toff + grp * 8);
        r.b0b = *(const u32x4*)(bd + toff + grp * 8 + 4);
        r.b1a = *(const u32x4*)(bd + toff + 32 + grp * 8);
        r.b1b = *(const u32x4*)(bd + toff + 32 + grp * 8 + 4);
        return r;
    };
    auto compute = [&](const unsigned int* buf, const SR& S) {
#pragma unroll
        for (int ks = 0; ks < 2; ++ks) {
            const short8 tA = ks ? S.t01 : S.t00;
            const short8 tB = ks ? S.t11 : S.t10;
            const u32x4 ba = ks ? S.b1a : S.b0a;
            const u32x4 bb = ks ? S.b1b : S.b0b;
            const int cb = ks * 8 + grp * 2;
            const i32x4 q0 = *(const i32x4*)&buf[li * 64 + (cb ^ li) * 4];
            const i32x4 q1 = *(const i32x4*)&buf[li * 64 + ((cb + 1) ^ li) * 4];
            const short8 A = buildQ(Rv, ba, bb, q0, q1);
            c0 = __builtin_amdgcn_mfma_f32_16x16x32_bf16(A, tA, c0, 0, 0, 0);
            c1 = __builtin_amdgcn_mfma_f32_16x16x32_bf16(A, tB, c1, 0, 0, 0);
            dn = __builtin_amdgcn_mfma_f32_16x16x32_bf16(A, bones, dn, 0, 0, 0);
        }
    };

    SR S[2];
    stage(0, 0);                       // 1 issue (oldest)
    S[0] = loadR(0);                   // 8 issues
    stage(1, JSTEP);                   // 1 issue (newest)
    asm volatile("s_waitcnt vmcnt(1)" ::: "memory");   // buf0 + S0 ready; buf1 in flight
    __builtin_amdgcn_s_barrier();
    __builtin_amdgcn_sched_barrier(0);

#pragma unroll
    for (int t = 0; t < NSTEPS; ++t) {
        if (t + 1 < NSTEPS) S[(t + 1) & 1] = loadR((t + 1) * JSTEP);
        if (t + 2 < NSTEPS) stage((t + 2) % 3, (t + 2) * JSTEP);

        compute(&adjbuf[t % 3][0], S[t & 1]);

        if (t + 2 < NSTEPS) {
            asm volatile("s_waitcnt vmcnt(1)" ::: "memory");  // drain stage(t+1)+loadR(t+1)
        } else if (t + 1 < NSTEPS) {
            asm volatile("s_waitcnt vmcnt(0)" ::: "memory");  // last prefetches
        }
        if (t + 1 < NSTEPS) {
            __builtin_amdgcn_s_barrier();
            __builtin_amdgcn_sched_barrier(0);
        }
    }

    // Epilogue: C layout col=li, row=grp*4+r.
    const int r0 = ibase + grp * 4;
    float* nb = numer + head * 32 + li;
#pragma unroll
    for (int r = 0; r < 4; ++r) {
        atomicAdd(nb + (size_t)(r0 + r) * 128, c0[r]);
        atomicAdd(nb + (size_t)(r0 + r) * 128 + 16, c1[r]);
    }
    if (li == 0) {
#pragma unroll
        for (int r = 0; r < 4; ++r)
            atomicAdd(denom + (r0 + r) * 4 + head, dn[r]);
    }
}

// Kernel 4: out = numer / denom
__global__ __launch_bounds__(256) void k4_fin(const float* __restrict__ numer,
                                              const float* __restrict__ denom,
                                              float* __restrict__ out) {
    const int idx = blockIdx.x * 256 + threadIdx.x;
    const int node = idx >> 7;
    const int headc = (idx & 127) >> 5;
    out[idx] = numer[idx] / denom[node * 4 + headc];
}

extern "C" void kernel_launch(void* const* d_in, const int* in_sizes, int n_in,
                              void* d_out, int out_size, void* d_ws, size_t ws_size,
                              hipStream_t stream) {
    const float* x = (const float*)d_in[0];
    const int* adj = (const int*)d_in[1];
    const float* W = (const float*)d_in[2];
    const float* asrc = (const float*)d_in[3];
    const float* adst = (const float*)d_in[4];
    float* out = (float*)d_out;

    char* ws = (char*)d_ws;
    float* numer = (float*)ws;                                     // 2 MB
    float* denom = (float*)(ws + (size_t)2097152);                 // 64 KB
    float* Rt = (float*)(ws + (size_t)2097152 + 65536);            // 64 KB
    unsigned* BDt = (unsigned*)(ws + (size_t)2097152 + 131072);    // 64 KB
    unsigned short* hT = (unsigned short*)(ws + (size_t)2097152 + 196608);  // 1 MB

    (void)hipMemsetAsync(numer, 0, 2097152 + 65536, stream);       // zero accumulators
    k1_proj<<<256, 256, 0, stream>>>(x, W, asrc, adst, hT, Rt, BDt);
    k3_main<<<dim3(NN / ROWS, SJ), 256, 0, stream>>>(adj, hT, Rt, BDt, numer, denom);
    k4_fin<<<2048, 256, 0, stream>>>(numer, denom, out);
}

// Round 11
// 57.449 us; speedup vs baseline: 1.1616x; 1.1616x over previous
//
#include <hip/hip_runtime.h>
#include <hip/hip_bf16.h>

#define NN 4096
#define SJ 8
#define JCH (NN / SJ)        // 512
#define JSTEP 64
#define NSTEPS (JCH / JSTEP) // 8
#define LOG2E 1.44269504f

typedef __attribute__((ext_vector_type(4))) float f32x4;
typedef __attribute__((ext_vector_type(4))) int i32x4;
typedef __attribute__((ext_vector_type(4))) unsigned int u32x4;
typedef __attribute__((ext_vector_type(8))) short short8;

// packed bf16 pair: (lo=bf16(a), hi=bf16(b)) in one dword (v_cvt_pk_bf16_f32)
__device__ __forceinline__ unsigned pk2(float a, float b) {
    float2 t; t.x = a; t.y = b;
    __hip_bfloat162 h = __float22bfloat162_rn(t);
    unsigned r;
    __builtin_memcpy(&r, &h, 4);
    return r;
}

__device__ __forceinline__ short8 load8_bf(const float* __restrict__ p) {
    f32x4 a = *(const f32x4*)p;
    f32x4 b = *(const f32x4*)(p + 4);
    u32x4 v = {pk2(a[0], a[1]), pk2(a[2], a[3]), pk2(b[0], b[1]), pk2(b[2], b[3])};
    return __builtin_bit_cast(short8, v);
}

// Kernel 1: h = x @ W^T (bf16 MFMA). Epilogue:
//   Rt[h][i]  = exp(-0.8*es_i)   (f32; exp(es) factor cancels in softmax)
//   BDt[h][j] = pack_bf16(exp(ed_j), exp(0.2*ed_j))
//   hT[h*32+d][j] = bf16 h, transposed via per-wave LDS tile (coalesced stores)
__global__ __launch_bounds__(256) void k1_proj(
        const float* __restrict__ x, const float* __restrict__ W,
        const float* __restrict__ asrc, const float* __restrict__ adst,
        unsigned short* __restrict__ hT, float* __restrict__ Rt,
        unsigned* __restrict__ BDt) {
    __shared__ unsigned short ttile[4][32][16];   // 4 KB
    const int ibase = blockIdx.x * 16;
    const int w = threadIdx.x >> 6;
    const int lane = threadIdx.x & 63;
    const int grp = lane >> 4, li = lane & 15;

    const float* xrow = x + (ibase + li) * 128;
    const float* w0 = W + (w * 32 + li) * 128;
    const float* w1 = W + (w * 32 + 16 + li) * 128;

    f32x4 c0 = {0.f, 0.f, 0.f, 0.f}, c1 = {0.f, 0.f, 0.f, 0.f};
#pragma unroll
    for (int ko = 0; ko < 128; ko += 32) {
        const int kk = ko + grp * 8;
        short8 a = load8_bf(xrow + kk);
        short8 b0 = load8_bf(w0 + kk);
        short8 b1 = load8_bf(w1 + kk);
        c0 = __builtin_amdgcn_mfma_f32_16x16x32_bf16(a, b0, c0, 0, 0, 0);
        c1 = __builtin_amdgcn_mfma_f32_16x16x32_bf16(a, b1, c1, 0, 0, 0);
    }
    const float as0 = asrc[w * 32 + li], as1 = asrc[w * 32 + 16 + li];
    const float ad0 = adst[w * 32 + li], ad1 = adst[w * 32 + 16 + li];
    float pes[4], ped[4];
#pragma unroll
    for (int r = 0; r < 4; ++r) {
        pes[r] = c0[r] * as0 + c1[r] * as1;
        ped[r] = c0[r] * ad0 + c1[r] * ad1;
    }
#pragma unroll
    for (int m = 1; m < 16; m <<= 1) {
#pragma unroll
        for (int r = 0; r < 4; ++r) {
            pes[r] += __shfl_xor(pes[r], m);
            ped[r] += __shfl_xor(ped[r], m);
        }
    }
    if (li == 0) {
#pragma unroll
        for (int r = 0; r < 4; ++r) {
            const int row = ibase + grp * 4 + r;
            Rt[w * NN + row] = __builtin_amdgcn_exp2f(-0.8f * LOG2E * pes[r]);
            const float Bv = __builtin_amdgcn_exp2f(LOG2E * ped[r]);
            const float Dv = __builtin_amdgcn_exp2f(0.2f * LOG2E * ped[r]);
            BDt[w * NN + row] = pk2(Bv, Dv);
        }
    }
    unsigned short* tw = &ttile[w][0][0];
    {
        uint2 v0; v0.x = pk2(c0[0], c0[1]); v0.y = pk2(c0[2], c0[3]);
        uint2 v1; v1.x = pk2(c1[0], c1[1]); v1.y = pk2(c1[2], c1[3]);
        *(uint2*)&tw[li * 16 + grp * 4] = v0;
        *(uint2*)&tw[(li + 16) * 16 + grp * 4] = v1;
    }
    __syncthreads();
    const int d = lane >> 1, half = lane & 1;
    u32x4 v = *(const u32x4*)&ttile[w][d][half * 8];
    *(u32x4*)(hT + (size_t)(w * 32 + d) * NN + ibase + half * 8) = v;
}

// ---- inline-asm 16B loads (volatile: cannot be sunk/reordered vs each other) ----
__device__ __forceinline__ u32x4 gld0(const void* p) {
    u32x4 d; asm volatile("global_load_dwordx4 %0, %1, off" : "=&v"(d) : "v"(p)); return d;
}
__device__ __forceinline__ u32x4 gld16(const void* p) {
    u32x4 d; asm volatile("global_load_dwordx4 %0, %1, off offset:16" : "=&v"(d) : "v"(p)); return d;
}
__device__ __forceinline__ u32x4 gld64(const void* p) {
    u32x4 d; asm volatile("global_load_dwordx4 %0, %1, off offset:64" : "=&v"(d) : "v"(p)); return d;
}
__device__ __forceinline__ u32x4 gld128(const void* p) {
    u32x4 d; asm volatile("global_load_dwordx4 %0, %1, off offset:128" : "=&v"(d) : "v"(p)); return d;
}
__device__ __forceinline__ u32x4 gld144(const void* p) {
    u32x4 d; asm volatile("global_load_dwordx4 %0, %1, off offset:144" : "=&v"(d) : "v"(p)); return d;
}

// per-step register payload: 8 x u32x4 = 32 VGPR per slot
struct SR { u32x4 h0k0, h0k1, h1k0, h1k1, bd00, bd01, bd10, bd11; };

// issue 8 loads directly into the named slot fields (no struct copies)
#define LOADR(dst, toff) do {                                             \
    (dst).h0k0 = gld0(h0b + (toff));  (dst).h0k1 = gld64(h0b + (toff));   \
    (dst).h1k0 = gld0(h1b + (toff));  (dst).h1k1 = gld64(h1b + (toff));   \
    (dst).bd00 = gld0(bd + (toff));   (dst).bd01 = gld16(bd + (toff));    \
    (dst).bd10 = gld128(bd + (toff)); (dst).bd11 = gld144(bd + (toff));   \
} while (0)

// pin prefetched regs to post-waitcnt point (consumers read post-wait defs)
#define LAUNDER(s) asm volatile("" : "+v"((s).h0k0), "+v"((s).h0k1),      \
    "+v"((s).h1k0), "+v"((s).h1k1), "+v"((s).bd00), "+v"((s).bd01),       \
    "+v"((s).bd10), "+v"((s).bd11))

// q = adj * max(B, R*D) from packed bf16 {B,D} (R9's proven math, f32 compute)
__device__ __forceinline__ short8 buildQ(float R, const u32x4 ba, const u32x4 bb,
                                         const i32x4 q0, const i32x4 q1) {
    float p[8];
#pragma unroll
    for (int e = 0; e < 4; ++e) {
        const unsigned v = ba[e];
        const float B = __builtin_bit_cast(float, v << 16);
        const float D = __builtin_bit_cast(float, v & 0xFFFF0000u);
        const float m = fmaxf(B, R * D);
        p[e] = __builtin_bit_cast(float, __builtin_bit_cast(unsigned, m) & (0u - (unsigned)q0[e]));
    }
#pragma unroll
    for (int e = 0; e < 4; ++e) {
        const unsigned v = bb[e];
        const float B = __builtin_bit_cast(float, v << 16);
        const float D = __builtin_bit_cast(float, v & 0xFFFF0000u);
        const float m = fmaxf(B, R * D);
        p[4 + e] = __builtin_bit_cast(float, __builtin_bit_cast(unsigned, m) & (0u - (unsigned)q1[e]));
    }
    u32x4 u = {pk2(p[0], p[1]), pk2(p[2], p[3]), pk2(p[4], p[5]), pk2(p[6], p[7])};
    return __builtin_bit_cast(short8, u);
}

// Kernel 3: grid (128 i-tiles of 32 rows, SJ) x 256 thr, wave = head.
// Counted-vmcnt pipeline: tables via volatile-asm loads (depth-1, registers,
// laundered after the wait), adj via global_load_lds (depth-2, LDS triple-buf).
// sched_barrier(0) pins issue-group order so vmcnt(2) counts deterministically.
__global__ __launch_bounds__(256) void k3_main(
        const int* __restrict__ adj, const unsigned short* __restrict__ hT,
        const float* __restrict__ Rt, const unsigned* __restrict__ BDt,
        float* __restrict__ numer, float* __restrict__ denom) {
    __shared__ unsigned int adjbuf[3][32 * 64];   // 3 x 8 KB

    const int ibase = blockIdx.x * 32;
    const int jstart = blockIdx.y * JCH;
    const int head = threadIdx.x >> 6;
    const int lane = threadIdx.x & 63;
    const int grp = lane >> 4, li = lane & 15;

    const float R0 = Rt[head * NN + ibase + li];
    const float R1 = Rt[head * NN + ibase + 16 + li];
    const unsigned short* h0b = hT + (size_t)(head * 32 + li) * NN + jstart + grp * 8;
    const unsigned short* h1b = h0b + (size_t)16 * NN;
    const unsigned* bd = BDt + head * NN + jstart + grp * 8;
    const unsigned int* adju = (const unsigned int*)adj;

    // staging: wave stages rows head*8..+7; chunk-position li holds global
    // chunk li ^ (row&15) (LDS dest linear per rule 21), inverted on ds_read.
    const int Rw0 = head * 8 + grp, Rw1 = Rw0 + 4;
    const unsigned int* g0 = adju + (size_t)(ibase + Rw0) * NN + jstart + (li ^ (Rw0 & 15)) * 4;
    const unsigned int* g1 = adju + (size_t)(ibase + Rw1) * NN + jstart + (li ^ (Rw1 & 15)) * 4;

    f32x4 c00 = {0.f,0.f,0.f,0.f}, c01 = {0.f,0.f,0.f,0.f};
    f32x4 c10 = {0.f,0.f,0.f,0.f}, c11 = {0.f,0.f,0.f,0.f};
    f32x4 dn0 = {0.f,0.f,0.f,0.f}, dn1 = {0.f,0.f,0.f,0.f};
    short8 bones;
#pragma unroll
    for (int e = 0; e < 8; ++e) bones[e] = (short)0x3F80;  // bf16 1.0

    auto stage = [&](int slot, int s) {
        __builtin_amdgcn_global_load_lds(g0 + s * JSTEP, &adjbuf[slot][(head * 8) * 64], 16, 0, 0);
        __builtin_amdgcn_global_load_lds(g1 + s * JSTEP, &adjbuf[slot][(head * 8 + 4) * 64], 16, 0, 0);
    };
    auto compute = [&](const unsigned int* buf, const SR& S) {
#pragma unroll
        for (int ks = 0; ks < 2; ++ks) {
            const u32x4 ba = ks ? S.bd10 : S.bd00;
            const u32x4 bb = ks ? S.bd11 : S.bd01;
            const short8 tA = __builtin_bit_cast(short8, ks ? S.h0k1 : S.h0k0);
            const short8 tB = __builtin_bit_cast(short8, ks ? S.h1k1 : S.h1k0);
            const int cb = ks * 8 + grp * 2;
            const i32x4 q00 = *(const i32x4*)&buf[li * 64 + ((cb) ^ li) * 4];
            const i32x4 q01 = *(const i32x4*)&buf[li * 64 + ((cb + 1) ^ li) * 4];
            const i32x4 q10 = *(const i32x4*)&buf[(li + 16) * 64 + ((cb) ^ li) * 4];
            const i32x4 q11 = *(const i32x4*)&buf[(li + 16) * 64 + ((cb + 1) ^ li) * 4];
            const short8 A0 = buildQ(R0, ba, bb, q00, q01);
            const short8 A1 = buildQ(R1, ba, bb, q10, q11);
            c00 = __builtin_amdgcn_mfma_f32_16x16x32_bf16(A0, tA, c00, 0, 0, 0);
            c01 = __builtin_amdgcn_mfma_f32_16x16x32_bf16(A0, tB, c01, 0, 0, 0);
            c10 = __builtin_amdgcn_mfma_f32_16x16x32_bf16(A1, tA, c10, 0, 0, 0);
            c11 = __builtin_amdgcn_mfma_f32_16x16x32_bf16(A1, tB, c11, 0, 0, 0);
            dn0 = __builtin_amdgcn_mfma_f32_16x16x32_bf16(A0, bones, dn0, 0, 0, 0);
            dn1 = __builtin_amdgcn_mfma_f32_16x16x32_bf16(A1, bones, dn1, 0, 0, 0);
        }
    };

    SR S0, S1;
    stage(0, 0);
    __builtin_amdgcn_sched_barrier(0);
    LOADR(S0, 0);
    __builtin_amdgcn_sched_barrier(0);
    stage(1, 1);
    __builtin_amdgcn_sched_barrier(0);
    asm volatile("s_waitcnt vmcnt(2)" ::: "memory");   // buf0 + S0 ready; stage(1) in flight
    LAUNDER(S0);
    __builtin_amdgcn_s_barrier();
    __builtin_amdgcn_sched_barrier(0);

#pragma unroll
    for (int t = 0; t < NSTEPS; ++t) {
        SR& Scur = (t & 1) ? S1 : S0;
        SR& Snxt = (t & 1) ? S0 : S1;
        if (t + 1 < NSTEPS) { LOADR(Snxt, (t + 1) * JSTEP); }
        __builtin_amdgcn_sched_barrier(0);
        if (t + 2 < NSTEPS) stage((t + 2) % 3, t + 2);
        __builtin_amdgcn_sched_barrier(0);

        compute(&adjbuf[t % 3][0], Scur);

        if (t + 1 < NSTEPS) {
            if (t + 2 < NSTEPS) {
                asm volatile("s_waitcnt vmcnt(2)" ::: "memory");  // drain stage(t+1)+LOADR(t+1)
            } else {
                asm volatile("s_waitcnt vmcnt(0)" ::: "memory");
            }
            LAUNDER(Snxt);
            __builtin_amdgcn_s_barrier();
            __builtin_amdgcn_sched_barrier(0);
        }
    }

    // Epilogue: C layout col=li, row=grp*4+r.
    const int r0 = ibase + grp * 4;
    float* nb = numer + head * 32 + li;
#pragma unroll
    for (int r = 0; r < 4; ++r) {
        atomicAdd(nb + (size_t)(r0 + r) * 128, c00[r]);
        atomicAdd(nb + (size_t)(r0 + r) * 128 + 16, c01[r]);
        atomicAdd(nb + (size_t)(r0 + 16 + r) * 128, c10[r]);
        atomicAdd(nb + (size_t)(r0 + 16 + r) * 128 + 16, c11[r]);
    }
    if (li == 0) {
#pragma unroll
        for (int r = 0; r < 4; ++r) {
            atomicAdd(denom + (r0 + r) * 4 + head, dn0[r]);
            atomicAdd(denom + (r0 + 16 + r) * 4 + head, dn1[r]);
        }
    }
}

// Kernel 4: out = numer / denom
__global__ __launch_bounds__(256) void k4_fin(const float* __restrict__ numer,
                                              const float* __restrict__ denom,
                                              float* __restrict__ out) {
    const int idx = blockIdx.x * 256 + threadIdx.x;
    const int node = idx >> 7;
    const int headc = (idx & 127) >> 5;
    out[idx] = numer[idx] / denom[node * 4 + headc];
}

extern "C" void kernel_launch(void* const* d_in, const int* in_sizes, int n_in,
                              void* d_out, int out_size, void* d_ws, size_t ws_size,
                              hipStream_t stream) {
    const float* x = (const float*)d_in[0];
    const int* adj = (const int*)d_in[1];
    const float* W = (const float*)d_in[2];
    const float* asrc = (const float*)d_in[3];
    const float* adst = (const float*)d_in[4];
    float* out = (float*)d_out;

    char* ws = (char*)d_ws;
    float* numer = (float*)ws;                                     // 2 MB
    float* denom = (float*)(ws + (size_t)2097152);                 // 64 KB
    float* Rt = (float*)(ws + (size_t)2097152 + 65536);            // 64 KB
    unsigned* BDt = (unsigned*)(ws + (size_t)2097152 + 131072);    // 64 KB
    unsigned short* hT = (unsigned short*)(ws + (size_t)2097152 + 196608);  // 1 MB

    (void)hipMemsetAsync(numer, 0, 2097152 + 65536, stream);       // zero accumulators
    k1_proj<<<256, 256, 0, stream>>>(x, W, asrc, adst, hT, Rt, BDt);
    k3_main<<<dim3(128, SJ), 256, 0, stream>>>(adj, hT, Rt, BDt, numer, denom);
    k4_fin<<<2048, 256, 0, stream>>>(numer, denom, out);
}